// Round 7
// baseline (62464.917 us; speedup 1.0000x reference)
//
#include <hip/hip_runtime.h>
#include <float.h>

constexpr int SEQ  = 128;   // sentence length T
constexpr int D    = 256;   // DIM / STATEDIM
constexpr int G    = 1024;  // 4*DIM gate width
constexpr int NREL = 26;    // REL_COUNT + 1
constexpr int NENT = 7;

typedef float v2f __attribute__((ext_vector_type(2)));

// ---------------------------------------------------------------------------
// Generic strided transpose: out[k*rows + i] = in[i*in_stride + in_off + k]
// ---------------------------------------------------------------------------
__global__ void k_trans(const float* __restrict__ in, float* __restrict__ out,
                        int rows, int cols, int in_stride, int in_off)
{
    int idx = blockIdx.x * 256 + threadIdx.x;
    if (idx >= rows * cols) return;
    int i = idx % rows;
    int k = idx / rows;
    out[idx] = in[(size_t)i * in_stride + in_off + k];
}

// ---------------------------------------------------------------------------
// xg[t][j] = bih[j] + bhh[j] + sum_k wordvector[text[t]][k] * Wih[j][k]
// ---------------------------------------------------------------------------
__global__ __launch_bounds__(1024) void k_xg(
    const int* __restrict__ text, const float* __restrict__ wv,
    const float* __restrict__ Wih, const float* __restrict__ bih,
    const float* __restrict__ bhh, float* __restrict__ xg)
{
    int t = blockIdx.x, j = threadIdx.x;
    const float* x  = wv + (size_t)text[t] * D;
    const float* wr = Wih + (size_t)j * D;
    float acc = bih[j] + bhh[j];
    for (int k = 0; k < D; ++k) acc += x[k] * wr[k];
    xg[t * G + j] = acc;
}

// ---------------------------------------------------------------------------
// Sequential LSTM, one block per direction (grid=2), 1024 threads.
// ---------------------------------------------------------------------------
__global__ __launch_bounds__(1024) void k_lstm(
    const float* __restrict__ xgF, const float* __restrict__ xgB,
    const float* __restrict__ WHTF, const float* __restrict__ WHTB,
    float* __restrict__ wordin)
{
    int dir = blockIdx.x;
    const float* xg  = dir ? xgB  : xgF;
    const float* WHT = dir ? WHTB : WHTF;
    __shared__ float h[D], c[D], g[G];
    int j = threadIdx.x;
    if (j < D) { h[j] = 0.f; c[j] = 0.f; }
    __syncthreads();
    for (int s = 0; s < SEQ; ++s) {
        int t = dir ? (SEQ - 1 - s) : s;
        float acc = xg[t * G + j];
        for (int k = 0; k < D; ++k) acc += WHT[k * G + j] * h[k];
        g[j] = acc;
        __syncthreads();
        if (j < D) {
            float si = 1.f / (1.f + expf(-g[j]));
            float sf = 1.f / (1.f + expf(-g[D + j]));
            float gg = tanhf(g[2 * D + j]);
            float so = 1.f / (1.f + expf(-g[3 * D + j]));
            float cn = sf * c[j] + si * gg;
            float hn = so * tanhf(cn);
            c[j] = cn; h[j] = hn;
            wordin[t * (2 * D) + dir * D + j] = hn;
        }
        __syncthreads();
    }
}

// ---------------------------------------------------------------------------
// Parallel precompute after LSTM (TW/BW per word, RV per relation, EV per ent)
// ---------------------------------------------------------------------------
__global__ __launch_bounds__(256) void k_prep2(
    const float* __restrict__ wordin,
    const float* __restrict__ WTWT, const float* __restrict__ WBWT,
    const float* __restrict__ WTRT, const float* __restrict__ WBET,
    const float* __restrict__ relvec, const float* __restrict__ entvec,
    const float* __restrict__ btv, const float* __restrict__ bbv,
    float* __restrict__ TW, float* __restrict__ BW,
    float* __restrict__ RV, float* __restrict__ EV)
{
    int b = blockIdx.x, i = threadIdx.x;
    if (b < SEQ) {
        const float* w = wordin + b * (2 * D);
        float a1 = btv[i], a2 = bbv[i];
        for (int j = 0; j < 2 * D; ++j) {
            float wv = w[j];
            a1 += wv * WTWT[j * D + i];
            a2 += wv * WBWT[j * D + i];
        }
        TW[b * D + i] = a1;
        BW[b * D + i] = a2;
    } else if (b < SEQ + NREL) {
        int r = b - SEQ;
        const float* x = relvec + r * D;
        float a = 0.f;
        for (int k = 0; k < D; ++k) a += x[k] * WTRT[k * D + i];
        RV[r * D + i] = a;
    } else {
        int e = b - SEQ - NREL;
        const float* x = entvec + e * D;
        float a = 0.f;
        for (int k = 0; k < D; ++k) a += x[k] * WBET[k * D + i];
        EV[e * D + i] = a;
    }
}

// ---------------------------------------------------------------------------
// M1T[j*D + i] = sum_k WBGT[k*D+i] * Wtt[k*D+j]   (M1 = Wb_target @ Wtt)
// ---------------------------------------------------------------------------
__global__ __launch_bounds__(256) void k_m1(
    const float* __restrict__ WBGT, const float* __restrict__ Wtt,
    float* __restrict__ M1T)
{
    int j = blockIdx.x, i = threadIdx.x;
    float a = 0.f;
    for (int k = 0; k < D; ++k) a = fmaf(WBGT[k * D + i], Wtt[k * D + j], a);
    M1T[j * D + i] = a;
}

// c1[i] = sum_k WBGT[k*D+i] * btt[k]
__global__ __launch_bounds__(256) void k_c1(
    const float* __restrict__ WBGT, const float* __restrict__ btt,
    float* __restrict__ c1)
{
    int i = threadIdx.x;
    float a = 0.f;
    for (int k = 0; k < D; ++k) a = fmaf(WBGT[k * D + i], btt[k], a);
    c1[i] = a;
}

// ---------------------------------------------------------------------------
// Register-half pack: WB5R[tid*64 + kk] = Wb[i][768 + h*128 + kk]
//   tid = h*256+i (512 threads), kk < 64.
// ---------------------------------------------------------------------------
__global__ __launch_bounds__(256) void k_pack5r(
    const float* __restrict__ Wb, float* __restrict__ WB5R)
{
    int e = blockIdx.x * 256 + threadIdx.x;      // 0..32767
    int tid = e >> 6, kk = e & 63;
    int h = tid >> 8, i = tid & 255;
    WB5R[e] = Wb[(size_t)i * (5 * D) + 3 * D + h * 128 + kk];
}

// ---------------------------------------------------------------------------
// LDS-half pack, pre-arranged in the exact LDS layout (wave-contiguous f4):
//   float4 index f4 = (wv*16 + j)*64 + l  holds thread (wv*64+l)'s j-th float4
//   of its LDS k-chunk: Wb[i][768 + h*128 + 64 + j*4 + c]
// ---------------------------------------------------------------------------
__global__ __launch_bounds__(256) void k_pack5l(
    const float* __restrict__ Wb, float* __restrict__ WB5L)
{
    int f = blockIdx.x * 256 + threadIdx.x;      // 0..32767
    int f4 = f >> 2, c = f & 3;
    int l = f4 & 63, j = (f4 >> 6) & 15, wv = f4 >> 10;
    int tid = wv * 64 + l;
    int h = tid >> 8, i = tid & 255;
    WB5L[f] = Wb[(size_t)i * (5 * D) + 3 * D + h * 128 + 64 + j * 4 + c];
}

// ---------------------------------------------------------------------------
// Streamed split-k half-matvec (top steps): Wcol = W^T[k0*D + i] (k-major),
// x = LDS vector slice for this k-half (128 elements). 4 independent chains.
// ---------------------------------------------------------------------------
__device__ inline float mv_half(const float* __restrict__ Wcol,
                                const float* __restrict__ x)
{
    float a0 = 0.f, a1 = 0.f, a2 = 0.f, a3 = 0.f;
    #pragma unroll
    for (int kk = 0; kk < 128; kk += 4) {
        a0 = fmaf(Wcol[(kk + 0) * D], x[kk + 0], a0);
        a1 = fmaf(Wcol[(kk + 1) * D], x[kk + 1], a1);
        a2 = fmaf(Wcol[(kk + 2) * D], x[kk + 2], a2);
        a3 = fmaf(Wcol[(kk + 3) * D], x[kk + 3], a3);
    }
    return (a0 + a1) + (a2 + a3);
}

// ---------------------------------------------------------------------------
// Softmax + first-occurrence argmax over n values in lanes 0..n-1 of each
// W-lane group (reference-faithful: p = exp(l-max)/sum, argmax over p).
// ---------------------------------------------------------------------------
template<int W>
__device__ inline void grp_smax(float lv, int n, int lane, int& am, float& pm)
{
    float mx = lv;
    #pragma unroll
    for (int off = W / 2; off; off >>= 1) mx = fmaxf(mx, __shfl_xor(mx, off));
    float e  = (lane < n) ? expf(lv - mx) : 0.f;
    float se = e;
    #pragma unroll
    for (int off = W / 2; off; off >>= 1) se += __shfl_xor(se, off);
    float p  = (lane < n) ? (e / se) : -1.f;
    float q  = p;
    #pragma unroll
    for (int off = W / 2; off; off >>= 1) q = fmaxf(q, __shfl_xor(q, off));
    unsigned long long mask = __ballot(p == q);
    am = __ffsll((long long)mask) - 1;
    pm = q;
}

// ---------------------------------------------------------------------------
// Sequential main kernel: 1 block, 512 threads = 8 waves = 2 waves/SIMD.
// KEY INSIGHT (R1-R6 post-mortem): the 256x256 f32 bot weight matrix is
// 65536 floats = EXACTLY the per-CU VGPR budget (empirical law: budget =
// 65536/blockSize at every block size) -> full register residency is
// impossible; the allocator always spilled it (GBs of HBM scratch traffic).
// Here each thread keeps 64 weight floats in VGPRs (64 + ~50 working <= 128
// budget) and reads the other 64 from LDS (128 KB, wave-contiguous float4
// layout -> conflict-free ds_read_b128).
// ---------------------------------------------------------------------------
__global__ __launch_bounds__(512)
void k_main5(
    const float* __restrict__ TW,   const float* __restrict__ BW,
    const float* __restrict__ RV,   const float* __restrict__ EV,
    const float* __restrict__ WTMT, const float* __restrict__ WTBT,
    const float* __restrict__ WBTT, const float* __restrict__ M1T,
    const float* __restrict__ c1v,  const float* __restrict__ WB5R,
    const float* __restrict__ WB5L,
    const float* __restrict__ Wp,   const float* __restrict__ bp,
    const float* __restrict__ Wpl,  const float* __restrict__ bpl,
    const float* __restrict__ btb,  const float* __restrict__ bbt,
    float* __restrict__ out)
{
    const int tid  = threadIdx.x;
    const int lane = tid & 63;
    const int wv8  = tid >> 6;        // wave id 0..7
    const int lwv  = wv8 & 3;         // wave id within half
    const int h    = tid >> 8;        // k-half 0..1
    const int i    = tid & 255;       // output index
    const bool lower = (tid < 256);

    // --- LDS ---
    __shared__ __align__(16) float wlds[512 * 64];        // 128 KB weights
    __shared__ __align__(16) float xbuf[2][D];
    __shared__ __align__(16) float psA[2][D], psB[2][D];
    __shared__ __align__(16) float mem[D], outv[D];
    __shared__ __align__(16) float WrSh[NENT * D];
    __shared__ float lpart[4][32];
    __shared__ float brSh[8];

    // stage LDS weight half (global pre-packed in the exact LDS layout)
    {
        const float4* g4 = reinterpret_cast<const float4*>(WB5L);
        float4* w4 = reinterpret_cast<float4*>(wlds);
        #pragma unroll
        for (int it = 0; it < 16; ++it) w4[tid + it * 512] = g4[tid + it * 512];
    }

    // register-resident weight half (per-thread contiguous pack)
    v2f w2[32];
    {
        const float4* src = reinterpret_cast<const float4*>(WB5R) + tid * 16;
        #pragma unroll
        for (int k4 = 0; k4 < 16; ++k4) {
            float4 v = src[k4];
            w2[2 * k4 + 0] = (v2f){v.x, v.y};
            w2[2 * k4 + 1] = (v2f){v.z, v.w};
        }
    }
    // pin: forbid rematerialization of the weight loads
    #pragma unroll
    for (int k2 = 0; k2 < 32; ++k2) {
        double dp = __builtin_bit_cast(double, w2[k2]);
        asm volatile("" : "+v"(dp));
        w2[k2] = __builtin_bit_cast(v2f, dp);
    }

    // loop-invariant entity columns, register-resident (lower half only)
    float ev0 = 0.f, ev1 = 0.f, ev2 = 0.f, ev3 = 0.f,
          ev4 = 0.f, ev5 = 0.f, ev6 = 0.f;
    if (lower) {
        ev0 = EV[0 * D + i]; ev1 = EV[1 * D + i]; ev2 = EV[2 * D + i];
        ev3 = EV[3 * D + i]; ev4 = EV[4 * D + i]; ev5 = EV[5 * D + i];
        ev6 = EV[6 * D + i];
        mem[i] = 0.f;
    }
    __syncthreads();

    const float4* wbase =
        reinterpret_cast<const float4*>(wlds) + (size_t)wv8 * (16 * 64) + lane;

    const float* WTMh = WTMT + (size_t)h * 128 * D + i;
    const float* WTBh = WTBT + (size_t)h * 128 * D + i;
    const float* WBTh = WBTT + (size_t)h * 128 * D + i;
    const float* M1h  = M1T  + (size_t)h * 128 * D + i;

    int rel = 0;

    for (int t = 0; t < SEQ; ++t) {
        // ---- top step: outp = tanh(TW[t] + RV[rel] + Wt_m @ mem) ----
        psA[h][i] = mv_half(WTMh, mem + h * 128);
        __syncthreads();
        if (lower) {
            float tot = psA[0][i] + psA[1][i] +
                        TW[t * D + i] + RV[rel * D + i];
            float outp = tanhf(tot);
            outv[i] = outp;
            #pragma unroll 2
            for (int r = 0; r < NREL; ++r) {
                float pp = outp * Wp[r * D + i];
                #pragma unroll
                for (int off = 32; off; off >>= 1) pp += __shfl_xor(pp, off);
                if (lane == 0) lpart[lwv][r] = pp;
            }
        }
        __syncthreads();
        float lv = -FLT_MAX;
        if (lane < NREL)
            lv = lpart[0][lane] + lpart[1][lane] + lpart[2][lane] +
                 lpart[3][lane] + bp[lane];
        int am; float pm;
        grp_smax<32>(lv, NREL, lane, am, pm);
        if (tid == 0) { out[t] = (float)am; out[SEQ + t] = pm; }
        const int action = am;   // wave-uniform

        if (action > 0) {
            rel = action;
            // memb0 = Wtb@outp + btb ;  btm = M1@outp + c1  (tgt folded away)
            psA[h][i] = mv_half(WTBh, outv + h * 128);
            psB[h][i] = mv_half(M1h,  outv + h * 128);
            const size_t wbaseW = (size_t)(action - 1) * NENT * D;
            for (int k = tid; k < NENT * D; k += 512) WrSh[k] = Wpl[wbaseW + k];
            if (tid < NENT) brSh[tid] = bpl[(action - 1) * NENT + tid];
            __syncthreads();
            float btm = 0.f, bwc = 0.f;
            if (lower) {
                xbuf[0][i] = psA[0][i] + psA[1][i] + btb[i];
                btm = psB[0][i] + psB[1][i] + c1v[i];
                bwc = BW[i];          // prefetch BW row 0
            }
            __syncthreads();

            int p = 0, ab = 0;
            for (int s = 0; s < SEQ; ++s) {
                // -- half-matvec: 64 k from VGPRs + 64 k from LDS --
                const float4* xb =
                    reinterpret_cast<const float4*>(xbuf[p] + h * 128);
                v2f A0 = {0.f, 0.f}, A1 = {0.f, 0.f},
                    A2 = {0.f, 0.f}, A3 = {0.f, 0.f};
                #pragma unroll
                for (int k4 = 0; k4 < 16; k4 += 4) {
                    float4 x0 = xb[k4], x1 = xb[k4 + 1],
                           x2 = xb[k4 + 2], x3 = xb[k4 + 3];
                    A0 = __builtin_elementwise_fma(w2[2 * k4 + 0], (v2f){x0.x, x0.y}, A0);
                    A0 = __builtin_elementwise_fma(w2[2 * k4 + 1], (v2f){x0.z, x0.w}, A0);
                    A1 = __builtin_elementwise_fma(w2[2 * k4 + 2], (v2f){x1.x, x1.y}, A1);
                    A1 = __builtin_elementwise_fma(w2[2 * k4 + 3], (v2f){x1.z, x1.w}, A1);
                    A2 = __builtin_elementwise_fma(w2[2 * k4 + 4], (v2f){x2.x, x2.y}, A2);
                    A2 = __builtin_elementwise_fma(w2[2 * k4 + 5], (v2f){x2.z, x2.w}, A2);
                    A3 = __builtin_elementwise_fma(w2[2 * k4 + 6], (v2f){x3.x, x3.y}, A3);
                    A3 = __builtin_elementwise_fma(w2[2 * k4 + 7], (v2f){x3.z, x3.w}, A3);
                }
                #pragma unroll
                for (int j = 0; j < 16; j += 4) {
                    float4 wa = wbase[(j + 0) * 64], wb_ = wbase[(j + 1) * 64],
                           wc = wbase[(j + 2) * 64], wd  = wbase[(j + 3) * 64];
                    float4 xa = xb[16 + j],     xv = xb[17 + j],
                           xc = xb[18 + j],     xd = xb[19 + j];
                    A0 = __builtin_elementwise_fma((v2f){wa.x, wa.y}, (v2f){xa.x, xa.y}, A0);
                    A0 = __builtin_elementwise_fma((v2f){wa.z, wa.w}, (v2f){xa.z, xa.w}, A0);
                    A1 = __builtin_elementwise_fma((v2f){wb_.x, wb_.y}, (v2f){xv.x, xv.y}, A1);
                    A1 = __builtin_elementwise_fma((v2f){wb_.z, wb_.w}, (v2f){xv.z, xv.w}, A1);
                    A2 = __builtin_elementwise_fma((v2f){wc.x, wc.y}, (v2f){xc.x, xc.y}, A2);
                    A2 = __builtin_elementwise_fma((v2f){wc.z, wc.w}, (v2f){xc.z, xc.w}, A2);
                    A3 = __builtin_elementwise_fma((v2f){wd.x, wd.y}, (v2f){xd.x, xd.y}, A3);
                    A3 = __builtin_elementwise_fma((v2f){wd.z, wd.w}, (v2f){xd.z, xd.w}, A3);
                }
                v2f AS = (A0 + A1) + (A2 + A3);
                float ms = AS.x + AS.y;
                psA[h][i] = ms;
                __syncthreads();                       // barrier 1
                if (lower) {
                    float ev = (ab == 0) ? ev0 : (ab == 1) ? ev1 :
                               (ab == 2) ? ev2 : (ab == 3) ? ev3 :
                               (ab == 4) ? ev4 : (ab == 5) ? ev5 : ev6;
                    float tot = ms + psA[1][i] + bwc + ev + btm;
                    float ob = tanhf(tot);
                    xbuf[p ^ 1][i] = ob;
                    #pragma unroll
                    for (int r = 0; r < NENT; ++r) {
                        float pp = ob * WrSh[r * D + i];
                        #pragma unroll
                        for (int off = 32; off; off >>= 1)
                            pp += __shfl_xor(pp, off);
                        if (lane == 0) lpart[lwv][r] = pp;
                    }
                    int sn = (s + 1 < SEQ) ? s + 1 : s;
                    bwc = BW[sn * D + i];              // prefetch next row
                }
                __syncthreads();                       // barrier 2
                float lv2 = -FLT_MAX;
                if (lane < NENT)
                    lv2 = lpart[0][lane] + lpart[1][lane] + lpart[2][lane] +
                          lpart[3][lane] + brSh[lane];
                int am2; float pm2;
                grp_smax<8>(lv2, NENT, lane, am2, pm2);
                if (tid == 0) {
                    out[2 * SEQ + t * SEQ + s] = (float)am2;
                    out[2 * SEQ + SEQ * SEQ + t * SEQ + s] = pm2;
                }
                ab = am2;        // wave-uniform register, no LDS roundtrip
                p ^= 1;
            }
            // mem = Wbt @ membf + bbt
            psA[h][i] = mv_half(WBTh, xbuf[p] + h * 128);
            __syncthreads();
            if (lower) mem[i] = psA[0][i] + psA[1][i] + bbt[i];
            __syncthreads();
        } else {
            if (lower) mem[i] = outv[i];
            if (tid < SEQ) {
                out[2 * SEQ + t * SEQ + tid] = 0.f;
                out[2 * SEQ + SEQ * SEQ + t * SEQ + tid] = 0.f;
            }
            __syncthreads();
        }
    }
}

// ---------------------------------------------------------------------------
extern "C" void kernel_launch(void* const* d_in, const int* in_sizes, int n_in,
                              void* d_out, int out_size, void* d_ws, size_t ws_size,
                              hipStream_t stream)
{
    (void)in_sizes; (void)n_in; (void)out_size; (void)ws_size;
    const int*   text       = (const int*)  d_in[0];
    const float* wordvector = (const float*)d_in[1];
    const float* relvec     = (const float*)d_in[2];
    const float* entvec     = (const float*)d_in[3];
    const float* WihL = (const float*)d_in[4];  const float* WhhL = (const float*)d_in[5];
    const float* bihL = (const float*)d_in[6];  const float* bhhL = (const float*)d_in[7];
    const float* WihR = (const float*)d_in[8];  const float* WhhR = (const float*)d_in[9];
    const float* bihR = (const float*)d_in[10]; const float* bhhR = (const float*)d_in[11];
    const float* Wt   = (const float*)d_in[12]; const float* bt   = (const float*)d_in[13];
    const float* Wp   = (const float*)d_in[14]; const float* bp   = (const float*)d_in[15];
    const float* Wb   = (const float*)d_in[16]; const float* bb   = (const float*)d_in[17];
    const float* Wpl  = (const float*)d_in[18]; const float* bpl  = (const float*)d_in[19];
    const float* Wtt  = (const float*)d_in[20]; const float* btt  = (const float*)d_in[21];
    const float* Wtb  = (const float*)d_in[22]; const float* btb  = (const float*)d_in[23];
    const float* Wbt  = (const float*)d_in[24]; const float* bbt  = (const float*)d_in[25];

    float* ws = (float*)d_ws;
    size_t o = 0;
    auto take = [&](size_t n) { float* p = ws + o; o += n; return p; };
    float* XGF    = take(SEQ * G);
    float* XGB    = take(SEQ * G);
    float* WHLT   = take(D * G);
    float* WHRT   = take(D * G);
    float* WORDIN = take(SEQ * 2 * D);
    float* TW     = take(SEQ * D);
    float* BW     = take(SEQ * D);
    float* RVb    = take(NREL * D);
    float* EVb    = take(NENT * D);
    float* WTWT   = take(2 * D * D);
    float* WTRT   = take(D * D);
    float* WTMT   = take(D * D);
    float* WBWT   = take(2 * D * D);
    float* WBET   = take(D * D);
    float* WBGT   = take(D * D);
    float* WTBT   = take(D * D);
    float* WBTT   = take(D * D);
    float* M1T    = take(D * D);
    float* C1     = take(D);
    float* WB5R   = take(512 * 64);      // register-half pack
    float* WB5L   = take(512 * 64);      // LDS-half pack (LDS layout order)

    auto tr = [&](const float* in, float* outp, int rows, int cols, int stride, int off) {
        int n = rows * cols;
        k_trans<<<(n + 255) / 256, 256, 0, stream>>>(in, outp, rows, cols, stride, off);
    };
    tr(WhhL, WHLT, G, D, D, 0);          // WHLT[k*G + j] = WhhL[j][k]
    tr(WhhR, WHRT, G, D, D, 0);
    tr(Wt,  WTWT, D, 2 * D, G, 0);       // word part of Wt
    tr(Wt,  WTRT, D, D, G, 512);         // relvec part
    tr(Wt,  WTMT, D, D, G, 768);         // mem part
    tr(Wb,  WBWT, D, 2 * D, 5 * D, 0);   // word part of Wb
    tr(Wb,  WBET, D, D, 5 * D, 512);     // entvec part
    tr(Wb,  WBGT, D, D, 5 * D, 1024);    // target part (feeds M1/c1)
    tr(Wtb, WTBT, D, D, D, 0);
    tr(Wbt, WBTT, D, D, D, 0);

    k_m1<<<D, D, 0, stream>>>(WBGT, Wtt, M1T);
    k_c1<<<1, D, 0, stream>>>(WBGT, btt, C1);
    k_pack5r<<<128, 256, 0, stream>>>(Wb, WB5R);
    k_pack5l<<<128, 256, 0, stream>>>(Wb, WB5L);

    k_xg<<<SEQ, 1024, 0, stream>>>(text, wordvector, WihL, bihL, bhhL, XGF);
    k_xg<<<SEQ, 1024, 0, stream>>>(text, wordvector, WihR, bihR, bhhR, XGB);
    k_lstm<<<2, 1024, 0, stream>>>(XGF, XGB, WHLT, WHRT, WORDIN);
    k_prep2<<<SEQ + NREL + NENT, 256, 0, stream>>>(WORDIN, WTWT, WBWT, WTRT, WBET,
                                                   relvec, entvec, bt, bb,
                                                   TW, BW, RVb, EVb);
    k_main5<<<1, 512, 0, stream>>>(TW, BW, RVb, EVb, WTMT, WTBT, WBTT, M1T, C1,
                                   WB5R, WB5L, Wp, bp, Wpl, bpl, btb, bbt,
                                   (float*)d_out);
}